// Round 6
// baseline (866.232 us; speedup 1.0000x reference)
//
#include <hip/hip_runtime.h>

#define NEG_SLOPE 0.2f
#define HEADS 8
#define FEAT 16
#define HF 128     // HEADS*FEAT
#define FIN 128
#define BROWS 64   // rows per proj block
#define PITCH 136  // padded LDS row (bf16 elems): +8 → b128 reads 2-way (free)
#define BSHIFT 7   // 128 nodes per bucket
#define BNODES 128
#define MAXBUCK 512  // >= ceil(N/128); N=50000 -> 391
#define EPT 16       // binsort edges per thread (chunk = 4096/block)
#define AGGT 512     // bucket_agg threads (8 waves)

typedef __bf16 bf16x8 __attribute__((ext_vector_type(8)));
typedef float  f32x4  __attribute__((ext_vector_type(4)));

// ---- int64-vs-int32 edge_index hedge -------------------------------------
// Reference declares int64; indices < 50000, so an int64 (LE) buffer has all
// odd 32-bit words zero. Four zero samples from genuine int32: ~(1/5e4)^4.
__device__ __forceinline__ bool detect_i64(const int* ei) {
    return (ei[1] | ei[3] | ei[5] | ei[7]) == 0;
}
__device__ __forceinline__ int load_idx(const int* ei, long long pos, bool is64) {
    return is64 ? ei[2 * pos] : ei[pos];
}

__device__ __forceinline__ float bf2f(unsigned u) { return __uint_as_float(u << 16); }

// RNE float->bf16 (bit-level)
__device__ __forceinline__ unsigned short f2bf(float f) {
    unsigned u = __float_as_uint(f);
    unsigned r = u + 0x7fffu + ((u >> 16) & 1u);
    return (unsigned short)(r >> 16);
}

// ---- kernel: h = x @ W^T via bf16 MFMA + fused per-node logits ------------
__global__ __launch_bounds__(256) void proj_kernel(
    const float* __restrict__ x, const float* __restrict__ W,
    const float* __restrict__ att_src, const float* __restrict__ att_dst,
    unsigned short* __restrict__ hb, float* __restrict__ a_src,
    float* __restrict__ a_dst, int N)
{
    __shared__ unsigned short xs[BROWS * PITCH];  // reused for h tile
    __shared__ unsigned short wsl[FIN * PITCH];
    const int t = threadIdx.x;
    const int n0 = blockIdx.x * BROWS;

#pragma unroll
    for (int i = 0; i < 8; ++i) {
        const int f4 = i * 256 + t;          // 64 rows x 32 float4
        const int r = f4 >> 5, c4 = f4 & 31;
        const int rr = (n0 + r < N) ? (n0 + r) : (N - 1);
        const float4 v = ((const float4*)(x + (size_t)rr * FIN))[c4];
        unsigned short* p = &xs[r * PITCH + c4 * 4];
        p[0] = f2bf(v.x); p[1] = f2bf(v.y); p[2] = f2bf(v.z); p[3] = f2bf(v.w);
    }
#pragma unroll
    for (int i = 0; i < 16; ++i) {
        const int f4 = i * 256 + t;
        const int r = f4 >> 5, c4 = f4 & 31;
        const float4 v = ((const float4*)(W + (size_t)r * FIN))[c4];
        unsigned short* p = &wsl[r * PITCH + c4 * 4];
        p[0] = f2bf(v.x); p[1] = f2bf(v.y); p[2] = f2bf(v.z); p[3] = f2bf(v.w);
    }
    __syncthreads();

    const int w = t >> 6, lane = t & 63;
    const int lrow = lane & 15;
    const int lk = lane >> 4;
    const int r0 = w * 16;

    f32x4 acc[8];
#pragma unroll
    for (int i = 0; i < 8; ++i) { f32x4 z = {0.f, 0.f, 0.f, 0.f}; acc[i] = z; }

#pragma unroll
    for (int ks = 0; ks < 4; ++ks) {
        const int kb = ks * 32 + lk * 8;
        const bf16x8 af = *(const bf16x8*)&xs[(r0 + lrow) * PITCH + kb];
#pragma unroll
        for (int tt = 0; tt < 8; ++tt) {
            const bf16x8 bf = *(const bf16x8*)&wsl[(tt * 16 + lrow) * PITCH + kb];
            acc[tt] = __builtin_amdgcn_mfma_f32_16x16x32_bf16(af, bf, acc[tt], 0, 0, 0);
        }
    }
    __syncthreads();

#pragma unroll
    for (int tt = 0; tt < 8; ++tt) {
#pragma unroll
        for (int rg = 0; rg < 4; ++rg) {
            const int row = r0 + lk * 4 + rg;
            const int col = tt * 16 + lrow;
            xs[row * PITCH + col] = f2bf(acc[tt][rg]);
        }
    }
    __syncthreads();

#pragma unroll
    for (int i = 0; i < 8; ++i) {
        const int u4 = i * 256 + t;
        const int r = u4 >> 5, c4 = u4 & 31;
        if (n0 + r < N) {
            const unsigned short* p = &xs[r * PITCH + c4 * 4];
            ushort4 v; v.x = p[0]; v.y = p[1]; v.z = p[2]; v.w = p[3];
            ((ushort4*)hb)[(size_t)(n0 + r) * (HF / 4) + c4] = v;
        }
    }
#pragma unroll
    for (int i = 0; i < 2; ++i) {
        const int p = i * 256 + t;
        const int r = p >> 3, hd = p & 7;
        if (n0 + r < N) {
            float s = 0.f, d = 0.f;
#pragma unroll
            for (int j = 0; j < FEAT; ++j) {
                const float hv = bf2f(xs[r * PITCH + hd * FEAT + j]);
                s = fmaf(hv, att_src[hd * FEAT + j], s);
                d = fmaf(hv, att_dst[hd * FEAT + j], d);
            }
            a_src[(size_t)(n0 + r) * HEADS + hd] = s;
            a_dst[(size_t)(n0 + r) * HEADS + hd] = d;
        }
    }
}

// ---- bucket-sort CSR build ------------------------------------------------
__global__ __launch_bounds__(256) void init_small(int* __restrict__ ghist, int nb)
{
    const int i = blockIdx.x * 256 + threadIdx.x;
    if (i < nb) ghist[i] = 0;
}

// per-block LDS histogram of dst buckets, flush with global atomics
__global__ __launch_bounds__(256) void hist_kernel(
    const int* __restrict__ ei, int* __restrict__ ghist, int E, int nb)
{
    __shared__ int lh[MAXBUCK];
    const int t = threadIdx.x;
    for (int b = t; b < nb; b += 256) lh[b] = 0;
    __syncthreads();
    const bool is64 = detect_i64(ei);
    const int e0 = blockIdx.x * 2048;
#pragma unroll
    for (int i = 0; i < 8; ++i) {
        const int e = e0 + i * 256 + t;
        if (e < E) {
            const int d = load_idx(ei, (long long)E + e, is64);
            atomicAdd(&lh[d >> BSHIFT], 1);
        }
    }
    __syncthreads();
    for (int b = t; b < nb; b += 256) {
        const int c = lh[b];
        if (c) atomicAdd(&ghist[b], c);
    }
}

// single block: exclusive scan of bucket counts -> base & cursor
__global__ __launch_bounds__(512) void scan_buckets(
    const int* __restrict__ ghist, int* __restrict__ bucket_base,
    int* __restrict__ bucket_cursor, int nb, int E)
{
    __shared__ int tmp[512];
    const int t = threadIdx.x;
    const int v = (t < nb) ? ghist[t] : 0;
    tmp[t] = v;
    __syncthreads();
#pragma unroll
    for (int off = 1; off < 512; off <<= 1) {
        int y = (t >= off) ? tmp[t - off] : 0;
        __syncthreads();
        tmp[t] += y;
        __syncthreads();
    }
    if (t < nb) {
        const int excl = tmp[t] - v;
        bucket_base[t] = excl;
        bucket_cursor[t] = excl;
    }
    if (t == nb - 1) bucket_base[nb] = tmp[t];   // == E
}

// block-aggregated scatter: LDS hist -> ONE global atomic per (block,bucket)
// -> scatter via LDS cursors. Edges packed 4B: src | (dst<<16)  (N<=65536).
__global__ __launch_bounds__(256) void binsort_kernel(
    const int* __restrict__ ei, int* __restrict__ bucket_cursor,
    unsigned* __restrict__ ebuf, int E, int nb)
{
    __shared__ int lh[MAXBUCK];      // hist, then local cursor
    __shared__ int lbase[MAXBUCK];   // reserved global base per bucket
    const int t = threadIdx.x;
    const bool is64 = detect_i64(ei);
    const int e0 = blockIdx.x * (EPT * 256);

    for (int b = t; b < nb; b += 256) lh[b] = 0;
    __syncthreads();

    unsigned pk[EPT];
#pragma unroll
    for (int i = 0; i < EPT; ++i) {
        const int e = e0 + i * 256 + t;
        if (e < E) {
            const unsigned s = (unsigned)load_idx(ei, e, is64);
            const unsigned d = (unsigned)load_idx(ei, (long long)E + e, is64);
            pk[i] = s | (d << 16);            // s,d < 65536
            atomicAdd(&lh[d >> BSHIFT], 1);
        } else {
            pk[i] = 0xffffffffu;              // s=0xffff impossible (>=N)
        }
    }
    __syncthreads();
    for (int b = t; b < nb; b += 256) {
        const int c = lh[b];
        lbase[b] = c ? atomicAdd(&bucket_cursor[b], c) : 0;
        lh[b] = 0;                            // becomes local cursor
    }
    __syncthreads();
#pragma unroll
    for (int i = 0; i < EPT; ++i) {
        if (pk[i] != 0xffffffffu) {
            const int bkt = pk[i] >> (16 + BSHIFT);
            const int pos = lbase[bkt] + atomicAdd(&lh[bkt], 1);
            ebuf[pos] = pk[i];
        }
    }
}

// ---- fused aggregate: one block per bucket, LDS accumulator tile ----------
// Single-pass softmax: acc = sum(w*h), den = sum(w); out = acc/den + bias.
// acc layout permuted: feat f -> word (f>>1) + (f&1)*64 (stride-1 ds_add,
// conflict-free). Edges consumed unsorted straight from ebuf.
__global__ __launch_bounds__(AGGT) void bucket_agg(
    const unsigned* __restrict__ ebuf, const int* __restrict__ bucket_base,
    const float* __restrict__ a_src, const float* __restrict__ a_dst,
    const unsigned short* __restrict__ hb, const float* __restrict__ bias,
    float* __restrict__ out, int N)
{
    __shared__ float acc[BNODES * HF];      // 64 KB
    __shared__ float den[BNODES * HEADS];   // 4 KB
    const int b = blockIdx.x;
    const int t = threadIdx.x;
    const int base = bucket_base[b];
    const int cnt  = bucket_base[b + 1] - base;

    for (int i = t; i < BNODES * HF; i += AGGT) acc[i] = 0.f;
    for (int i = t; i < BNODES * HEADS; i += AGGT) den[i] = 0.f;
    __syncthreads();

    const int wv = t >> 6, lane = t & 63;
    const int hd = lane >> 3;               // head of feats 2*lane, 2*lane+1
    for (int j = wv; j < cnt; j += (AGGT / 64)) {
        const unsigned pk = ebuf[base + j];         // wave-uniform (broadcast)
        const int s  = pk & 0xffffu;
        const int dl = (pk >> 16) & (BNODES - 1);
        float v = a_src[s * HEADS + hd]
                + a_dst[((size_t)b * BNODES + dl) * HEADS + hd];
        v = v >= 0.f ? v : NEG_SLOPE * v;
        const float w = __expf(v);
        const unsigned p = ((const unsigned*)(hb + (size_t)s * HF))[lane];
        atomicAdd(&acc[dl * HF + lane],      w * bf2f(p & 0xffffu));  // feat 2*lane
        atomicAdd(&acc[dl * HF + 64 + lane], w * bf2f(p >> 16));      // feat 2*lane+1
        if ((lane & 7) == 0) atomicAdd(&den[dl * HEADS + hd], w);
    }
    __syncthreads();

    // normalize + bias + coalesced store (float2 per thread)
    for (int p = t; p < BNODES * 64; p += AGGT) {
        const int r = p >> 6, k = p & 63;    // node-local row, float2 index
        const int node = b * BNODES + r;
        if (node < N) {
            const float dv = den[r * HEADS + (k >> 3)] + 1e-16f;
            const float inv = 1.f / dv;
            const float2 b2 = ((const float2*)bias)[k];
            float2 o;
            o.x = acc[r * HF + k] * inv + b2.x;        // feat 2k
            o.y = acc[r * HF + 64 + k] * inv + b2.y;   // feat 2k+1
            ((float2*)out)[(size_t)node * 64 + k] = o;
        }
    }
}

extern "C" void kernel_launch(void* const* d_in, const int* in_sizes, int n_in,
                              void* d_out, int out_size, void* d_ws, size_t ws_size,
                              hipStream_t stream)
{
    const float* x       = (const float*)d_in[0];
    const float* W       = (const float*)d_in[1];
    const float* att_src = (const float*)d_in[2];
    const float* att_dst = (const float*)d_in[3];
    const float* bias    = (const float*)d_in[4];
    const int*   ei      = (const int*)d_in[5];
    float* out = (float*)d_out;

    const int N = in_sizes[0] / FIN;          // 50000
    const int E = in_sizes[5] / 2;            // 800000
    const int NBUCK = (N + BNODES - 1) >> BSHIFT;  // 391 (<= MAXBUCK)

    char* ws = (char*)d_ws;
    unsigned short* hb = (unsigned short*)ws; ws += (size_t)N * HF * 2;          // 12.8 MB
    unsigned* ebuf = (unsigned*)ws; ws += (size_t)E * 4;                         // 3.2 MB
    float* a_src  = (float*)ws; ws += (size_t)N * HEADS * sizeof(float);         // 1.6 MB
    float* a_dst  = (float*)ws; ws += (size_t)N * HEADS * sizeof(float);         // 1.6 MB
    int* ghist        = (int*)ws; ws += (size_t)MAXBUCK * sizeof(int);
    int* bucket_base  = (int*)ws; ws += ((size_t)MAXBUCK + 1) * sizeof(int);
    int* bucket_cursor= (int*)ws;

    hipLaunchKernelGGL(init_small, dim3((NBUCK + 255) / 256), dim3(256), 0, stream,
                       ghist, NBUCK);
    hipLaunchKernelGGL(proj_kernel, dim3((N + BROWS - 1) / BROWS), dim3(256), 0, stream,
                       x, W, att_src, att_dst, hb, a_src, a_dst, N);
    hipLaunchKernelGGL(hist_kernel, dim3((E + 2047) / 2048), dim3(256), 0, stream,
                       ei, ghist, E, NBUCK);
    hipLaunchKernelGGL(scan_buckets, dim3(1), dim3(512), 0, stream,
                       ghist, bucket_base, bucket_cursor, NBUCK, E);
    hipLaunchKernelGGL(binsort_kernel, dim3((E + EPT * 256 - 1) / (EPT * 256)), dim3(256),
                       0, stream, ei, bucket_cursor, ebuf, E, NBUCK);
    hipLaunchKernelGGL(bucket_agg, dim3(NBUCK), dim3(AGGT), 0, stream,
                       ebuf, bucket_base, a_src, a_dst, hb, bias, out, N);
}

// Round 7
// 177.079 us; speedup vs baseline: 4.8918x; 4.8918x over previous
//
#include <hip/hip_runtime.h>

#define NEG_SLOPE 0.2f
#define HEADS 8
#define FEAT 16
#define HF 128     // HEADS*FEAT
#define FIN 128
#define BROWS 64   // rows per proj block
#define PITCH 136  // padded LDS row (bf16 elems): +8 → b128 reads 2-way (free)
#define BSHIFT 7   // 128 nodes per bucket
#define BNODES 128
#define MAXBUCK 512  // >= ceil(N/128); N=50000 -> 391
#define EPT 16       // binsort edges per thread (chunk = 4096/block)

typedef __bf16 bf16x8 __attribute__((ext_vector_type(8)));
typedef float  f32x4  __attribute__((ext_vector_type(4)));

// ---- int64-vs-int32 edge_index hedge -------------------------------------
// Reference declares int64; indices < 50000, so an int64 (LE) buffer has all
// odd 32-bit words zero. Four zero samples from genuine int32: ~(1/5e4)^4.
__device__ __forceinline__ bool detect_i64(const int* ei) {
    return (ei[1] | ei[3] | ei[5] | ei[7]) == 0;
}
__device__ __forceinline__ int load_idx(const int* ei, long long pos, bool is64) {
    return is64 ? ei[2 * pos] : ei[pos];
}

__device__ __forceinline__ float bf2f(unsigned u) { return __uint_as_float(u << 16); }

// RNE float->bf16 (bit-level)
__device__ __forceinline__ unsigned short f2bf(float f) {
    unsigned u = __float_as_uint(f);
    unsigned r = u + 0x7fffu + ((u >> 16) & 1u);
    return (unsigned short)(r >> 16);
}

// ---- kernel: h = x @ W^T via bf16 MFMA + fused per-node logits ------------
__global__ __launch_bounds__(256) void proj_kernel(
    const float* __restrict__ x, const float* __restrict__ W,
    const float* __restrict__ att_src, const float* __restrict__ att_dst,
    unsigned short* __restrict__ hb, float* __restrict__ a_src,
    float* __restrict__ a_dst, int N)
{
    __shared__ unsigned short xs[BROWS * PITCH];  // reused for h tile
    __shared__ unsigned short wsl[FIN * PITCH];
    const int t = threadIdx.x;
    const int n0 = blockIdx.x * BROWS;

#pragma unroll
    for (int i = 0; i < 8; ++i) {
        const int f4 = i * 256 + t;          // 64 rows x 32 float4
        const int r = f4 >> 5, c4 = f4 & 31;
        const int rr = (n0 + r < N) ? (n0 + r) : (N - 1);
        const float4 v = ((const float4*)(x + (size_t)rr * FIN))[c4];
        unsigned short* p = &xs[r * PITCH + c4 * 4];
        p[0] = f2bf(v.x); p[1] = f2bf(v.y); p[2] = f2bf(v.z); p[3] = f2bf(v.w);
    }
#pragma unroll
    for (int i = 0; i < 16; ++i) {
        const int f4 = i * 256 + t;
        const int r = f4 >> 5, c4 = f4 & 31;
        const float4 v = ((const float4*)(W + (size_t)r * FIN))[c4];
        unsigned short* p = &wsl[r * PITCH + c4 * 4];
        p[0] = f2bf(v.x); p[1] = f2bf(v.y); p[2] = f2bf(v.z); p[3] = f2bf(v.w);
    }
    __syncthreads();

    const int w = t >> 6, lane = t & 63;
    const int lrow = lane & 15;
    const int lk = lane >> 4;
    const int r0 = w * 16;

    f32x4 acc[8];
#pragma unroll
    for (int i = 0; i < 8; ++i) { f32x4 z = {0.f, 0.f, 0.f, 0.f}; acc[i] = z; }

#pragma unroll
    for (int ks = 0; ks < 4; ++ks) {
        const int kb = ks * 32 + lk * 8;
        const bf16x8 af = *(const bf16x8*)&xs[(r0 + lrow) * PITCH + kb];
#pragma unroll
        for (int tt = 0; tt < 8; ++tt) {
            const bf16x8 bf = *(const bf16x8*)&wsl[(tt * 16 + lrow) * PITCH + kb];
            acc[tt] = __builtin_amdgcn_mfma_f32_16x16x32_bf16(af, bf, acc[tt], 0, 0, 0);
        }
    }
    __syncthreads();

#pragma unroll
    for (int tt = 0; tt < 8; ++tt) {
#pragma unroll
        for (int rg = 0; rg < 4; ++rg) {
            const int row = r0 + lk * 4 + rg;
            const int col = tt * 16 + lrow;
            xs[row * PITCH + col] = f2bf(acc[tt][rg]);
        }
    }
    __syncthreads();

#pragma unroll
    for (int i = 0; i < 8; ++i) {
        const int u4 = i * 256 + t;
        const int r = u4 >> 5, c4 = u4 & 31;
        if (n0 + r < N) {
            const unsigned short* p = &xs[r * PITCH + c4 * 4];
            ushort4 v; v.x = p[0]; v.y = p[1]; v.z = p[2]; v.w = p[3];
            ((ushort4*)hb)[(size_t)(n0 + r) * (HF / 4) + c4] = v;
        }
    }
#pragma unroll
    for (int i = 0; i < 2; ++i) {
        const int p = i * 256 + t;
        const int r = p >> 3, hd = p & 7;
        if (n0 + r < N) {
            float s = 0.f, d = 0.f;
#pragma unroll
            for (int j = 0; j < FEAT; ++j) {
                const float hv = bf2f(xs[r * PITCH + hd * FEAT + j]);
                s = fmaf(hv, att_src[hd * FEAT + j], s);
                d = fmaf(hv, att_dst[hd * FEAT + j], d);
            }
            a_src[(size_t)(n0 + r) * HEADS + hd] = s;
            a_dst[(size_t)(n0 + r) * HEADS + hd] = d;
        }
    }
}

// ---- bucket-sort CSR build ------------------------------------------------
__global__ __launch_bounds__(256) void init_small(int* __restrict__ ghist, int nb)
{
    const int i = blockIdx.x * 256 + threadIdx.x;
    if (i < nb) ghist[i] = 0;
}

// per-block LDS histogram of dst buckets, flush with global atomics
__global__ __launch_bounds__(256) void hist_kernel(
    const int* __restrict__ ei, int* __restrict__ ghist, int E, int nb)
{
    __shared__ int lh[MAXBUCK];
    const int t = threadIdx.x;
    for (int b = t; b < nb; b += 256) lh[b] = 0;
    __syncthreads();
    const bool is64 = detect_i64(ei);
    const int e0 = blockIdx.x * 2048;
#pragma unroll
    for (int i = 0; i < 8; ++i) {
        const int e = e0 + i * 256 + t;
        if (e < E) {
            const int d = load_idx(ei, (long long)E + e, is64);
            atomicAdd(&lh[d >> BSHIFT], 1);
        }
    }
    __syncthreads();
    for (int b = t; b < nb; b += 256) {
        const int c = lh[b];
        if (c) atomicAdd(&ghist[b], c);
    }
}

// single block: exclusive scan of bucket counts -> base & cursor; row_start[N]=E
__global__ __launch_bounds__(512) void scan_buckets(
    const int* __restrict__ ghist, int* __restrict__ bucket_base,
    int* __restrict__ bucket_cursor, int* __restrict__ row_start,
    int nb, int N, int E)
{
    __shared__ int tmp[512];
    const int t = threadIdx.x;
    const int v = (t < nb) ? ghist[t] : 0;
    tmp[t] = v;
    __syncthreads();
#pragma unroll
    for (int off = 1; off < 512; off <<= 1) {
        int y = (t >= off) ? tmp[t - off] : 0;
        __syncthreads();
        tmp[t] += y;
        __syncthreads();
    }
    if (t < nb) {
        const int excl = tmp[t] - v;
        bucket_base[t] = excl;
        bucket_cursor[t] = excl;
    }
    if (t == nb - 1) bucket_base[nb] = tmp[t];   // == E
    if (t == 0) row_start[N] = E;
}

// block-aggregated scatter: LDS hist -> ONE global atomic per (block,bucket)
// -> scatter via LDS cursors. Edges packed 4B: src | (dst<<16)  (N<=65536).
__global__ __launch_bounds__(256) void binsort_kernel(
    const int* __restrict__ ei, int* __restrict__ bucket_cursor,
    unsigned* __restrict__ ebuf, int E, int nb)
{
    __shared__ int lh[MAXBUCK];      // hist, then local cursor
    __shared__ int lbase[MAXBUCK];   // reserved global base per bucket
    const int t = threadIdx.x;
    const bool is64 = detect_i64(ei);
    const int e0 = blockIdx.x * (EPT * 256);

    for (int b = t; b < nb; b += 256) lh[b] = 0;
    __syncthreads();

    unsigned pk[EPT];
#pragma unroll
    for (int i = 0; i < EPT; ++i) {
        const int e = e0 + i * 256 + t;
        if (e < E) {
            const unsigned s = (unsigned)load_idx(ei, e, is64);
            const unsigned d = (unsigned)load_idx(ei, (long long)E + e, is64);
            pk[i] = s | (d << 16);            // s,d < 65536
            atomicAdd(&lh[d >> BSHIFT], 1);
        } else {
            pk[i] = 0xffffffffu;              // s=0xffff impossible (>=N)
        }
    }
    __syncthreads();
    for (int b = t; b < nb; b += 256) {
        const int c = lh[b];
        lbase[b] = c ? atomicAdd(&bucket_cursor[b], c) : 0;
        lh[b] = 0;                            // becomes local cursor
    }
    __syncthreads();
#pragma unroll
    for (int i = 0; i < EPT; ++i) {
        if (pk[i] != 0xffffffffu) {
            const int bkt = pk[i] >> (16 + BSHIFT);
            const int pos = lbase[bkt] + atomicAdd(&lh[bkt], 1);
            ebuf[pos] = pk[i];
        }
    }
}

// one block per bucket: LDS counting sort over the 128 local nodes.
// Emits row_start + csr_src, no global atomics, contiguous writes.
__global__ __launch_bounds__(256) void bucket_csr(
    const unsigned* __restrict__ ebuf,
    const int* __restrict__ bucket_base,
    int* __restrict__ row_start, int* __restrict__ csr_src, int N)
{
    __shared__ int cnts[BNODES], sc[BNODES], cur[BNODES];
    const int b = blockIdx.x;
    const int t = threadIdx.x;
    const int base = bucket_base[b];
    const int cnt = bucket_base[b + 1] - base;

    if (t < BNODES) cnts[t] = 0;
    __syncthreads();
    for (int j = t; j < cnt; j += 256)
        atomicAdd(&cnts[(ebuf[base + j] >> 16) & (BNODES - 1)], 1);
    __syncthreads();
    if (t < BNODES) sc[t] = cnts[t];
    __syncthreads();
#pragma unroll
    for (int off = 1; off < BNODES; off <<= 1) {
        int y = (t < BNODES && t >= off) ? sc[t - off] : 0;
        __syncthreads();
        if (t < BNODES) sc[t] += y;
        __syncthreads();
    }
    if (t < BNODES) {
        const int excl = sc[t] - cnts[t];
        const int node = b * BNODES + t;
        if (node < N) row_start[node] = base + excl;
        cur[t] = excl;
    }
    __syncthreads();
    for (int j = t; j < cnt; j += 256) {
        const unsigned p = ebuf[base + j];
        const int dl = (p >> 16) & (BNODES - 1);
        const int ofs = atomicAdd(&cur[dl], 1);
        csr_src[base + ofs] = (int)(p & 0xffffu);   // src < 65536
    }
}

// ---- aggregate: one wave per dst node, SINGLE-PASS softmax ----------------
// acc = sum(w*h), den = sum(w), w = exp(leakyrelu(e)); out = acc/den + bias.
// Max-shift cancels in the ratio; logits are O(5) so exp is fp32-safe.
__global__ __launch_bounds__(64) void agg_kernel(
    const int* __restrict__ csr_src, const int* __restrict__ row_start,
    const float* __restrict__ a_src, const float* __restrict__ a_dst,
    const unsigned short* __restrict__ hb, const float* __restrict__ bias,
    float* __restrict__ out)
{
    __shared__ int   srcbuf[64];
    __shared__ float wbuf[64 * HEADS];
    const int d = blockIdx.x;
    const int t = threadIdx.x;
    const int hd = t >> 3, sub = t & 7;
    const int beg = row_start[d], end = row_start[d + 1];
    const float adh = a_dst[d * HEADS + hd];

    float acc0 = 0.f, acc1 = 0.f, den = 0.f;
    for (int c = beg; c < end; c += 64) {
        const int m = min(64, end - c);
        if (t < m) srcbuf[t] = csr_src[c + t];
        __syncthreads();
        for (int j = sub; j < m; j += 8) {
            const int s = srcbuf[j];
            float v = a_src[s * HEADS + hd] + adh;
            v = v >= 0.f ? v : NEG_SLOPE * v;
            wbuf[j * HEADS + hd] = __expf(v);
        }
        __syncthreads();
        for (int j = 0; j < m; ++j) {
            const int s = srcbuf[j];
            const float w = wbuf[j * HEADS + hd];
            const unsigned p = *(const unsigned*)(hb + (size_t)s * HF + 2 * t);
            acc0 = fmaf(w, bf2f(p & 0xffffu), acc0);
            acc1 = fmaf(w, bf2f(p >> 16), acc1);
            den += w;
        }
        __syncthreads();
    }
    const float inv = 1.f / (den + 1e-16f);
    const float2 b2 = ((const float2*)bias)[t];
    float2 o2;
    o2.x = fmaf(acc0, inv, b2.x);
    o2.y = fmaf(acc1, inv, b2.y);
    ((float2*)out)[(size_t)d * (HF / 2) + t] = o2;
}

extern "C" void kernel_launch(void* const* d_in, const int* in_sizes, int n_in,
                              void* d_out, int out_size, void* d_ws, size_t ws_size,
                              hipStream_t stream)
{
    const float* x       = (const float*)d_in[0];
    const float* W       = (const float*)d_in[1];
    const float* att_src = (const float*)d_in[2];
    const float* att_dst = (const float*)d_in[3];
    const float* bias    = (const float*)d_in[4];
    const int*   ei      = (const int*)d_in[5];
    float* out = (float*)d_out;

    const int N = in_sizes[0] / FIN;          // 50000
    const int E = in_sizes[5] / 2;            // 800000
    const int NBUCK = (N + BNODES - 1) >> BSHIFT;  // 391 (<= MAXBUCK)

    char* ws = (char*)d_ws;
    unsigned short* hb = (unsigned short*)ws; ws += (size_t)N * HF * 2;          // 12.8 MB
    unsigned* ebuf = (unsigned*)ws; ws += (size_t)E * 4;                         // 3.2 MB
    float* a_src  = (float*)ws; ws += (size_t)N * HEADS * sizeof(float);         // 1.6 MB
    float* a_dst  = (float*)ws; ws += (size_t)N * HEADS * sizeof(float);         // 1.6 MB
    int* csr_src   = (int*)ws;  ws += (size_t)E * sizeof(int);                   // 3.2 MB
    int* row_start = (int*)ws;  ws += ((size_t)N + 1) * sizeof(int);
    int* ghist        = (int*)ws; ws += (size_t)MAXBUCK * sizeof(int);
    int* bucket_base  = (int*)ws; ws += ((size_t)MAXBUCK + 1) * sizeof(int);
    int* bucket_cursor= (int*)ws;

    hipLaunchKernelGGL(init_small, dim3((NBUCK + 255) / 256), dim3(256), 0, stream,
                       ghist, NBUCK);
    hipLaunchKernelGGL(proj_kernel, dim3((N + BROWS - 1) / BROWS), dim3(256), 0, stream,
                       x, W, att_src, att_dst, hb, a_src, a_dst, N);
    hipLaunchKernelGGL(hist_kernel, dim3((E + 2047) / 2048), dim3(256), 0, stream,
                       ei, ghist, E, NBUCK);
    hipLaunchKernelGGL(scan_buckets, dim3(1), dim3(512), 0, stream,
                       ghist, bucket_base, bucket_cursor, row_start, NBUCK, N, E);
    hipLaunchKernelGGL(binsort_kernel, dim3((E + EPT * 256 - 1) / (EPT * 256)), dim3(256),
                       0, stream, ei, bucket_cursor, ebuf, E, NBUCK);
    hipLaunchKernelGGL(bucket_csr, dim3(NBUCK), dim3(256), 0, stream,
                       ebuf, bucket_base, row_start, csr_src, N);
    hipLaunchKernelGGL(agg_kernel, dim3(N), dim3(64), 0, stream,
                       csr_src, row_start, a_src, a_dst, hb, bias, out);
}